// Round 23
// baseline (528.667 us; speedup 1.0000x reference)
//
#include <hip/hip_runtime.h>

#define IN_CH 1024
#define INTER 512
#define NEXP  128
#define TPE   512
#define TTOT  (NEXP*TPE)   // 65536 tokens

typedef __bf16 bf16x8  __attribute__((ext_vector_type(8)));
typedef __bf16 bf16x4v __attribute__((ext_vector_type(4)));
typedef float  f32x4   __attribute__((ext_vector_type(4)));

// ISA-pinned staging load ("=&v" early-clobber: R8 abort lesson; never let
// these spill -> 1 blk/CU only, R9 NaN lesson).
#define GLOAD(dst, p) \
  asm volatile("global_load_dwordx4 %0, %1, off" : "=&v"(dst) : "v"(p))

// vmcnt wait + scheduler fence (rule #18).
#define VM_WAIT() do { \
  asm volatile("s_waitcnt vmcnt(0)" ::: "memory"); \
  __builtin_amdgcn_sched_barrier(0); } while (0)

#define PHASE_SYNC() do { \
  __builtin_amdgcn_s_barrier(); \
  asm volatile("s_waitcnt lgkmcnt(0)" ::: "memory"); \
  __builtin_amdgcn_sched_barrier(0); \
  __builtin_amdgcn_s_setprio(1); } while (0)
#define PHASE_END() do { \
  __builtin_amdgcn_s_setprio(0); \
  __builtin_amdgcn_s_barrier(); } while (0)

// Async global->LDS, 16B/lane: LDS dest = wave-uniform base + lane*16
// (linear); swizzle via inverse-permuted per-lane GLOBAL source (rule #21).
#define GLDS16(gsrc, ldst) \
  __builtin_amdgcn_global_load_lds( \
      (const __attribute__((address_space(1))) unsigned int*)(gsrc), \
      (__attribute__((address_space(3))) unsigned int*)(ldst), 16, 0, 0)

// ---------------- Kernel 0: xbf = bf16(x), linear, MLP-batched --------------
// 390 MB of traffic; 16 INDEPENDENT float4 loads issued before any convert
// (R20's grid-stride version serialized loads -> 3.9 TB/s; this targets ~5.5).
__global__ __launch_bounds__(256) void xcvt_kernel(
    const float* __restrict__ x, __bf16* __restrict__ xbf)
{
  const size_t base = (size_t)blockIdx.x * 2048 + threadIdx.x;  // chunk id
  float4 lo[8], hi[8];
#pragma unroll
  for (int i = 0; i < 8; ++i) {
    const size_t cid = base + (size_t)i*256;
    lo[i] = *(const float4*)(x + cid*8);
    hi[i] = *(const float4*)(x + cid*8 + 4);
  }
#pragma unroll
  for (int i = 0; i < 8; ++i) {
    const size_t cid = base + (size_t)i*256;
    bf16x8 r;
    r[0]=(__bf16)lo[i].x; r[1]=(__bf16)lo[i].y; r[2]=(__bf16)lo[i].z; r[3]=(__bf16)lo[i].w;
    r[4]=(__bf16)hi[i].x; r[5]=(__bf16)hi[i].y; r[6]=(__bf16)hi[i].z; r[7]=(__bf16)hi[i].w;
    *(bf16x8*)(xbf + cid*8) = r;
  }
}

// ---------------- Kernel A2: h = silu(x@w1^T+b1)*(x@w3^T+b3) -----------------
// R20 VERBATIM (268 us measured): moe_out-shaped machine. BM=128 tok x
// BN=64 f dual-gemm, BK=64; A (xbf, bf16) via global_load_lds with
// idxs-gathered inverse-swizzled per-lane sources; B1/B3 reg-staged
// fp32->bf16. 64 KB LDS dbuf -> 2 blk/CU. P0/P1 counted-vmcnt phases.
__global__ __launch_bounds__(512) void moe_h2_kernel(
    const __bf16* __restrict__ xbf, const int* __restrict__ idxs,
    const float* __restrict__ w1w, const float* __restrict__ w1b,
    const float* __restrict__ w3w, const float* __restrict__ w3b,
    __bf16* __restrict__ hbuf)
{
  __shared__ __align__(16) ushort sA [2][128*64];   // 32 KB
  __shared__ __align__(16) ushort sB1[2][64*64];    // 16 KB
  __shared__ __align__(16) ushort sB3[2][64*64];    // 16 KB

  // XCD swizzle: 4096 blocks, 512/XCD
  const int blk = (blockIdx.x & 7) * (NEXP*32/8) + (blockIdx.x >> 3);
  const int e   = blk >> 5;
  const int tl  = blk & 31;
  const int tm  = tl >> 3, tn = tl & 7;   // tm: 128-tok tile, tn: 64-f tile

  const int tid  = threadIdx.x;
  const int lane = tid & 63;
  const int wid  = tid >> 6;
  const int wm   = wid >> 1;       // 0..3 -> 32-row slice
  const int wn   = wid & 1;        // 0..1 -> 32-col slice

  const int arow0 = wid*16 + (lane>>3);
  const int asc0  = (lane&7) ^ (arow0&7);
  const int asc1  = (lane&7) ^ ((arow0+8)&7);
  const int tokA0 = idxs[e*TPE + tm*128 + arow0];
  const int tokA1 = idxs[e*TPE + tm*128 + arow0 + 8];
  const __bf16* ag0 = xbf + (size_t)tokA0*IN_CH + (asc0<<3);
  const __bf16* ag1 = xbf + (size_t)tokA1*IN_CH + (asc1<<3);
  const int aslot0 = (wid*128)      * 8;   // ushort index of wave region
  const int aslot1 = (wid*128 + 64) * 8;

  const int r0   = tid >> 4;          // 0..31
  const int c4   = tid & 15;
  const int swzB = ((((c4>>1) ^ (r0&7))<<3) | ((c4&1)<<2));
  const float* b1p = w1w + ((size_t)e*INTER + tn*64 + r0)*IN_CH + (c4<<2);
  const float* b3p = w3w + ((size_t)e*INTER + tn*64 + r0)*IN_CH + (c4<<2);

  f32x4 acc1[2][2], acc3[2][2];
#pragma unroll
  for (int a = 0; a < 2; ++a)
#pragma unroll
    for (int b = 0; b < 2; ++b) {
      acc1[a][b] = (f32x4){0.f,0.f,0.f,0.f};
      acc3[a][b] = (f32x4){0.f,0.f,0.f,0.f};
    }

  float4 wv1[2], wv3[2];

  auto gldsA = [&](int buf, int kof) {
    GLDS16(ag0 + kof, &sA[buf][aslot0]);
    GLDS16(ag1 + kof, &sA[buf][aslot1]);
  };
  auto loadsB = [&](int kof) {
    wv1[0] = *(const float4*)(b1p + kof);
    wv1[1] = *(const float4*)(b1p + (size_t)32*IN_CH + kof);
    wv3[0] = *(const float4*)(b3p + kof);
    wv3[1] = *(const float4*)(b3p + (size_t)32*IN_CH + kof);
  };
  auto cvt4 = [](const float4& v) {
    bf16x4v b;
    b[0]=(__bf16)v.x; b[1]=(__bf16)v.y; b[2]=(__bf16)v.z; b[3]=(__bf16)v.w;
    return b;
  };
  auto storesB = [&](int buf) {
    *(bf16x4v*)&sB1[buf][ r0      *64 + swzB] = cvt4(wv1[0]);
    *(bf16x4v*)&sB1[buf][(r0 + 32)*64 + swzB] = cvt4(wv1[1]);
    *(bf16x4v*)&sB3[buf][ r0      *64 + swzB] = cvt4(wv3[0]);
    *(bf16x4v*)&sB3[buf][(r0 + 32)*64 + swzB] = cvt4(wv3[1]);
  };
  auto rdA = [&](int buf, int ks, bf16x8 af[2]) {
    const int k8 = (ks<<2) + (lane>>4);
#pragma unroll
    for (int mi = 0; mi < 2; ++mi) {
      const int r = wm*32 + mi*16 + (lane&15);
      af[mi] = *(const bf16x8*)&sA[buf][r*64 + ((k8 ^ (r&7))<<3)];
    }
  };
  auto rdB = [&](int buf, int ks, bf16x8 bq[2], bf16x8 bt[2]) {
    const int k8 = (ks<<2) + (lane>>4);
#pragma unroll
    for (int ni = 0; ni < 2; ++ni) {
      const int r   = wn*32 + ni*16 + (lane&15);
      const int off = r*64 + ((k8 ^ (r&7))<<3);
      bq[ni] = *(const bf16x8*)&sB1[buf][off];
      bt[ni] = *(const bf16x8*)&sB3[buf][off];
    }
  };

  // prologue: A(t0) glds + B(t0) regs; drain; stage B; B(t1) in flight
  gldsA(0, 0);
  loadsB(0);
  VM_WAIT();
  storesB(0);
  loadsB(64);
  asm volatile("s_waitcnt lgkmcnt(0)" ::: "memory");
  __builtin_amdgcn_s_barrier();

  int cur = 0;
  const int NT = IN_CH/64;
  for (int kt = 0; kt < NT; ++kt) {
    bf16x8 af[2], bq[2], bt[2];

    // P0: reads ks0 | drain B(t+1) -> sB(t+1) | issue A-glds(t+1) | B(t+2)
    rdA(cur, 0, af);
    rdB(cur, 0, bq, bt);
    if (kt < NT - 1) {
      VM_WAIT();
      storesB(cur ^ 1);
      gldsA(cur ^ 1, (kt+1)*64);
      __builtin_amdgcn_sched_barrier(0);   // pin glds before B loads
    }
    if (kt < NT - 2) loadsB((kt+2)*64);
    PHASE_SYNC();
#pragma unroll
    for (int mi = 0; mi < 2; ++mi)
#pragma unroll
      for (int ni = 0; ni < 2; ++ni) {
        acc1[mi][ni] = __builtin_amdgcn_mfma_f32_16x16x32_bf16(af[mi], bq[ni], acc1[mi][ni], 0, 0, 0);
        acc3[mi][ni] = __builtin_amdgcn_mfma_f32_16x16x32_bf16(af[mi], bt[ni], acc3[mi][ni], 0, 0, 0);
      }
    PHASE_END();

    // P1: reads ks1; vmcnt(4) leaves B(t+2) flying, guarantees glds(t+1)
    rdA(cur, 1, af);
    rdB(cur, 1, bq, bt);
    PHASE_SYNC();
#pragma unroll
    for (int mi = 0; mi < 2; ++mi)
#pragma unroll
      for (int ni = 0; ni < 2; ++ni) {
        acc1[mi][ni] = __builtin_amdgcn_mfma_f32_16x16x32_bf16(af[mi], bq[ni], acc1[mi][ni], 0, 0, 0);
        acc3[mi][ni] = __builtin_amdgcn_mfma_f32_16x16x32_bf16(af[mi], bt[ni], acc3[mi][ni], 0, 0, 0);
      }
    __builtin_amdgcn_s_setprio(0);
    if (kt < NT - 2)      asm volatile("s_waitcnt vmcnt(4)" ::: "memory");
    else if (kt < NT - 1) asm volatile("s_waitcnt vmcnt(0)" ::: "memory");
    __builtin_amdgcn_s_barrier();

    cur ^= 1;
  }

  // epilogue: bias + SwiGLU, store bf16 h tile
  const int rowbase = tm*128 + wm*32;
  const int colbase = tn*64  + wn*32;
#pragma unroll
  for (int ni = 0; ni < 2; ++ni) {
    const int fc = colbase + ni*16 + (lane&15);
    const float b1v = w1b[e*INTER + fc];
    const float b3v = w3b[e*INTER + fc];
#pragma unroll
    for (int mi = 0; mi < 2; ++mi) {
#pragma unroll
      for (int j = 0; j < 4; ++j) {
        const int rl = rowbase + mi*16 + ((lane>>4)<<2) + j;
        const float h1 = acc1[mi][ni][j] + b1v;
        const float h3 = acc3[mi][ni][j] + b3v;
        const float s  = h1 / (1.0f + __expf(-h1));
        hbuf[((size_t)e*TPE + rl)*INTER + fc] = (__bf16)(s * h3);
      }
    }
  }
}

// ---------------- Kernel B: out = h @ w2^T + b2, scattered (R17 verbatim) ---
__global__ __launch_bounds__(512) void moe_out_kernel(
    const __bf16* __restrict__ hbuf, const float* __restrict__ w2w,
    const float* __restrict__ w2b, const int* __restrict__ idxs,
    float* __restrict__ out)
{
  __shared__ __align__(16) ushort sA[2][128*64];
  __shared__ __align__(16) ushort sB[2][128*64];

  const int blk = (blockIdx.x & 7) * (NEXP*32/8) + (blockIdx.x >> 3);
  const int e   = blk >> 5;
  const int tl  = blk & 31;
  const int tm  = tl >> 3, tn = tl & 7;

  const int tid  = threadIdx.x;
  const int lane = tid & 63;
  const int wid  = tid >> 6;
  const int wm   = wid >> 1;
  const int wn   = wid & 1;

  const int arow0 = wid*16 + (lane>>3);
  const int asc0  = (lane&7) ^ (arow0&7);
  const int asc1  = (lane&7) ^ ((arow0+8)&7);
  const __bf16* ag0 = hbuf + ((size_t)e*TPE + tm*128 + arow0    )*INTER + (asc0<<3);
  const __bf16* ag1 = hbuf + ((size_t)e*TPE + tm*128 + arow0 + 8)*INTER + (asc1<<3);
  const int aslot0 = (wid*128)      * 8;
  const int aslot1 = (wid*128 + 64) * 8;

  const int r0   = tid >> 4;
  const int c4   = tid & 15;
  const int swzB = ((((c4>>1) ^ (r0&7))<<3) | ((c4&1)<<2));
  const float* bp = w2w + ((size_t)e*IN_CH + tn*128 + r0)*INTER + (c4<<2);

  f32x4 acc[2][4];
#pragma unroll
  for (int a = 0; a < 2; ++a)
#pragma unroll
    for (int b = 0; b < 4; ++b) acc[a][b] = (f32x4){0.f,0.f,0.f,0.f};

  float4 wv[4];

  auto gldsA = [&](int buf, int kof) {
    GLDS16(ag0 + kof, &sA[buf][aslot0]);
    GLDS16(ag1 + kof, &sA[buf][aslot1]);
  };
  auto loadsB = [&](int kof) {
#pragma unroll
    for (int i = 0; i < 4; ++i)
      wv[i] = *(const float4*)(bp + (size_t)(32*i)*INTER + kof);
  };
  auto storesB = [&](int buf) {
#pragma unroll
    for (int i = 0; i < 4; ++i) {
      bf16x4v b;
      b[0]=(__bf16)wv[i].x; b[1]=(__bf16)wv[i].y; b[2]=(__bf16)wv[i].z; b[3]=(__bf16)wv[i].w;
      *(bf16x4v*)&sB[buf][(r0 + 32*i)*64 + swzB] = b;
    }
  };
  auto rdA = [&](int buf, int ks, bf16x8 af[2]) {
    const int k8 = (ks<<2) + (lane>>4);
#pragma unroll
    for (int mi = 0; mi < 2; ++mi) {
      const int r = wm*32 + mi*16 + (lane&15);
      af[mi] = *(const bf16x8*)&sA[buf][r*64 + ((k8 ^ (r&7))<<3)];
    }
  };
  auto rdB = [&](int buf, int ks, bf16x8 bfr[4]) {
    const int k8 = (ks<<2) + (lane>>4);
#pragma unroll
    for (int ni = 0; ni < 4; ++ni) {
      const int r = wn*64 + ni*16 + (lane&15);
      bfr[ni] = *(const bf16x8*)&sB[buf][r*64 + ((k8 ^ (r&7))<<3)];
    }
  };

  gldsA(0, 0);
  loadsB(0);
  VM_WAIT();
  storesB(0);
  loadsB(64);
  asm volatile("s_waitcnt lgkmcnt(0)" ::: "memory");
  __builtin_amdgcn_s_barrier();

  int cur = 0;
  const int NT = INTER/64;
  for (int kt = 0; kt < NT; ++kt) {
    bf16x8 af[2], bfr[4];

    rdA(cur, 0, af);
    rdB(cur, 0, bfr);
    if (kt < NT - 1) {
      VM_WAIT();
      storesB(cur ^ 1);
      gldsA(cur ^ 1, (kt+1)*64);
      __builtin_amdgcn_sched_barrier(0);
    }
    if (kt < NT - 2) loadsB((kt+2)*64);
    PHASE_SYNC();
#pragma unroll
    for (int mi = 0; mi < 2; ++mi)
#pragma unroll
      for (int ni = 0; ni < 4; ++ni)
        acc[mi][ni] = __builtin_amdgcn_mfma_f32_16x16x32_bf16(af[mi], bfr[ni], acc[mi][ni], 0, 0, 0);
    PHASE_END();

    rdA(cur, 1, af);
    rdB(cur, 1, bfr);
    PHASE_SYNC();
#pragma unroll
    for (int mi = 0; mi < 2; ++mi)
#pragma unroll
      for (int ni = 0; ni < 4; ++ni)
        acc[mi][ni] = __builtin_amdgcn_mfma_f32_16x16x32_bf16(af[mi], bfr[ni], acc[mi][ni], 0, 0, 0);
    __builtin_amdgcn_s_setprio(0);
    if (kt < NT - 2)      asm volatile("s_waitcnt vmcnt(4)" ::: "memory");
    else if (kt < NT - 1) asm volatile("s_waitcnt vmcnt(0)" ::: "memory");
    __builtin_amdgcn_s_barrier();

    cur ^= 1;
  }

  const int rowbase = tm*128 + wm*32;
  const int colbase = tn*128 + wn*64;
  float b2v[4];
#pragma unroll
  for (int ni = 0; ni < 4; ++ni)
    b2v[ni] = w2b[e*IN_CH + colbase + ni*16 + (lane&15)];
#pragma unroll
  for (int mi = 0; mi < 2; ++mi) {
#pragma unroll
    for (int j = 0; j < 4; ++j) {
      const int rl  = rowbase + mi*16 + ((lane>>4)<<2) + j;
      const int tok = idxs[e*TPE + rl];
      float* orow = out + (size_t)tok*IN_CH;
#pragma unroll
      for (int ni = 0; ni < 4; ++ni)
        orow[colbase + ni*16 + (lane&15)] = acc[mi][ni][j] + b2v[ni];
    }
  }
}

// ---------------- Fallback moe_h (R19) if ws too small ----------------------
__global__ __launch_bounds__(512) void moe_h_kernel(
    const float* __restrict__ x, const int* __restrict__ idxs,
    const float* __restrict__ w1w, const float* __restrict__ w1b,
    const float* __restrict__ w3w, const float* __restrict__ w3b,
    __bf16* __restrict__ hbuf)
{
  __shared__ __align__(16) ushort sA [2][128*64];
  __shared__ __align__(16) ushort sB1[2][128*64];
  __shared__ __align__(16) ushort sB3[2][128*64];

  const int blk = (blockIdx.x & 7) * (NEXP*16/8) + (blockIdx.x >> 3);
  const int e   = blk >> 4;
  const int tl  = blk & 15;
  const int tm  = tl >> 2, tn = tl & 3;

  const int tid  = threadIdx.x;
  const int lane = tid & 63;
  const int wid  = tid >> 6;
  const int wm   = wid >> 1;
  const int wn   = wid & 1;

  const int rA = tid >> 3;
  const int c  = tid & 7;
  const int swzc = ((c ^ (rA&7))<<3);
  const int so0 = rA*64 + swzc;
  const int so1 = (rA+64)*64 + swzc;

  const int tok0 = idxs[e*TPE + tm*128 + rA];
  const int tok1 = idxs[e*TPE + tm*128 + rA + 64];
  const float* ap0 = x + (size_t)tok0*IN_CH + (c<<3);
  const float* ap1 = x + (size_t)tok1*IN_CH + (c<<3);
  const float* q0p = w1w + ((size_t)e*INTER + tn*128 + rA)*IN_CH + (c<<3);
  const float* q1p = q0p + (size_t)64*IN_CH;
  const float* t0p = w3w + ((size_t)e*INTER + tn*128 + rA)*IN_CH + (c<<3);
  const float* t1p = t0p + (size_t)64*IN_CH;

  f32x4 acc1[2][4], acc3[2][4];
#pragma unroll
  for (int a = 0; a < 2; ++a)
#pragma unroll
    for (int b = 0; b < 4; ++b) {
      acc1[a][b] = (f32x4){0.f,0.f,0.f,0.f};
      acc3[a][b] = (f32x4){0.f,0.f,0.f,0.f};
    }

  f32x4 a0l,a0h, a1l,a1h, q0l,q0h, q1l,q1h, t0l,t0h, t1l,t1h;

  auto loads = [&](int kof) {
    GLOAD(a0l, ap0 + kof); GLOAD(a0h, ap0 + kof + 4);
    GLOAD(a1l, ap1 + kof); GLOAD(a1h, ap1 + kof + 4);
    GLOAD(q0l, q0p + kof); GLOAD(q0h, q0p + kof + 4);
    GLOAD(q1l, q1p + kof); GLOAD(q1h, q1p + kof + 4);
    GLOAD(t0l, t0p + kof); GLOAD(t0h, t0p + kof + 4);
    GLOAD(t1l, t1p + kof); GLOAD(t1h, t1p + kof + 4);
  };
  auto cvt8 = [](const f32x4& lo, const f32x4& hi) {
    bf16x8 r;
    r[0]=(__bf16)lo[0]; r[1]=(__bf16)lo[1]; r[2]=(__bf16)lo[2]; r[3]=(__bf16)lo[3];
    r[4]=(__bf16)hi[0]; r[5]=(__bf16)hi[1]; r[6]=(__bf16)hi[2]; r[7]=(__bf16)hi[3];
    return r;
  };
  auto stores = [&](int buf) {
    VM_WAIT();
    *(bf16x8*)&sA [buf][so0] = cvt8(a0l, a0h);
    *(bf16x8*)&sA [buf][so1] = cvt8(a1l, a1h);
    *(bf16x8*)&sB1[buf][so0] = cvt8(q0l, q0h);
    *(bf16x8*)&sB1[buf][so1] = cvt8(q1l, q1h);
    *(bf16x8*)&sB3[buf][so0] = cvt8(t0l, t0h);
    *(bf16x8*)&sB3[buf][so1] = cvt8(t1l, t1h);
  };
  auto mfma_tile = [&](int buf) {
#pragma unroll
    for (int ks = 0; ks < 2; ++ks) {
      bf16x8 af[2], bq[4], bt[4];
      const int k8 = (ks<<2) + (lane>>4);
#pragma unroll
      for (int mi = 0; mi < 2; ++mi) {
        const int r = wm*32 + mi*16 + (lane&15);
        af[mi] = *(const bf16x8*)&sA[buf][r*64 + ((k8 ^ (r&7))<<3)];
      }
#pragma unroll
      for (int ni = 0; ni < 4; ++ni) {
        const int r   = wn*64 + ni*16 + (lane&15);
        const int off = r*64 + ((k8 ^ (r&7))<<3);
        bq[ni] = *(const bf16x8*)&sB1[buf][off];
        bt[ni] = *(const bf16x8*)&sB3[buf][off];
      }
#pragma unroll
      for (int mi = 0; mi < 2; ++mi)
#pragma unroll
        for (int ni = 0; ni < 4; ++ni) {
          acc1[mi][ni] = __builtin_amdgcn_mfma_f32_16x16x32_bf16(af[mi], bq[ni], acc1[mi][ni], 0, 0, 0);
          acc3[mi][ni] = __builtin_amdgcn_mfma_f32_16x16x32_bf16(af[mi], bt[ni], acc3[mi][ni], 0, 0, 0);
        }
    }
  };

  loads(0);
  stores(0);
  loads(64);
  asm volatile("s_waitcnt lgkmcnt(0)" ::: "memory");
  __builtin_amdgcn_s_barrier();

  int cur = 0;
  const int NT = IN_CH/64;
  for (int kt = 0; kt < NT; ++kt) {
    if (kt < NT - 1) stores(cur ^ 1);
    if (kt < NT - 2) loads((kt+2)*64);
    __builtin_amdgcn_s_setprio(1);
    mfma_tile(cur);
    __builtin_amdgcn_s_setprio(0);
    asm volatile("s_waitcnt lgkmcnt(0)" ::: "memory");
    __builtin_amdgcn_s_barrier();
    cur ^= 1;
  }

  const int rowbase = tm*128 + wm*32;
  const int colbase = tn*128 + wn*64;
#pragma unroll
  for (int ni = 0; ni < 4; ++ni) {
    const int fc = colbase + ni*16 + (lane&15);
    const float b1v = w1b[e*INTER + fc];
    const float b3v = w3b[e*INTER + fc];
#pragma unroll
    for (int mi = 0; mi < 2; ++mi) {
#pragma unroll
      for (int j = 0; j < 4; ++j) {
        const int rl = rowbase + mi*16 + ((lane>>4)<<2) + j;
        const float h1 = acc1[mi][ni][j] + b1v;
        const float h3 = acc3[mi][ni][j] + b3v;
        const float s  = h1 / (1.0f + __expf(-h1));
        hbuf[((size_t)e*TPE + rl)*INTER + fc] = (__bf16)(s * h3);
      }
    }
  }
}

extern "C" void kernel_launch(void* const* d_in, const int* in_sizes, int n_in,
                              void* d_out, int out_size, void* d_ws, size_t ws_size,
                              hipStream_t stream) {
  const float* x    = (const float*)d_in[0];
  const int*   idxs = (const int*)d_in[1];
  const float* w1w  = (const float*)d_in[2];
  const float* w1b  = (const float*)d_in[3];
  const float* w2w  = (const float*)d_in[4];
  const float* w2b  = (const float*)d_in[5];
  const float* w3w  = (const float*)d_in[6];
  const float* w3b  = (const float*)d_in[7];
  float* out = (float*)d_out;

  const size_t XBF = (size_t)TTOT * IN_CH * sizeof(__bf16);        // 134 MB
  const size_t HB  = (size_t)NEXP * TPE * INTER * sizeof(__bf16);  //  67 MB

  if (ws_size >= XBF + HB) {
    __bf16* xbf  = (__bf16*)d_ws;
    __bf16* hbuf = (__bf16*)((char*)d_ws + XBF);
    xcvt_kernel<<<dim3(4096), dim3(256), 0, stream>>>(x, xbf);
    moe_h2_kernel<<<dim3(NEXP*32), dim3(512), 0, stream>>>(
        xbf, idxs, w1w, w1b, w3w, w3b, hbuf);
    moe_out_kernel<<<dim3(NEXP*32), dim3(512), 0, stream>>>(
        hbuf, w2w, w2b, idxs, out);
  } else {
    __bf16* hbuf = (__bf16*)d_ws;
    moe_h_kernel<<<dim3(NEXP*16), dim3(512), 0, stream>>>(
        x, idxs, w1w, w1b, w3w, w3b, hbuf);
    moe_out_kernel<<<dim3(NEXP*32), dim3(512), 0, stream>>>(
        hbuf, w2w, w2b, idxs, out);
  }
}

// Round 24
// 482.533 us; speedup vs baseline: 1.0956x; 1.0956x over previous
//
#include <hip/hip_runtime.h>

#define IN_CH 1024
#define INTER 512
#define NEXP  128
#define TPE   512

typedef __bf16 bf16x8  __attribute__((ext_vector_type(8)));
typedef __bf16 bf16x4v __attribute__((ext_vector_type(4)));
typedef float  f32x4   __attribute__((ext_vector_type(4)));

// ISA-pinned staging load ("=&v" early-clobber: R8 abort lesson; never let
// these spill -> 1 blk/CU only, R9 NaN lesson).
#define GLOAD(dst, p) \
  asm volatile("global_load_dwordx4 %0, %1, off" : "=&v"(dst) : "v"(p))

// vmcnt wait + scheduler fence (rule #18).
#define VM_WAIT() do { \
  asm volatile("s_waitcnt vmcnt(0)" ::: "memory"); \
  __builtin_amdgcn_sched_barrier(0); } while (0)

#define PHASE_SYNC() do { \
  __builtin_amdgcn_s_barrier(); \
  asm volatile("s_waitcnt lgkmcnt(0)" ::: "memory"); \
  __builtin_amdgcn_sched_barrier(0); \
  __builtin_amdgcn_s_setprio(1); } while (0)
#define PHASE_END() do { \
  __builtin_amdgcn_s_setprio(0); \
  __builtin_amdgcn_s_barrier(); } while (0)

// Async global->LDS, 16B per lane: LDS dest = wave-uniform base + lane*16
// (linear); swizzle achieved by inverse-permuting the per-lane GLOBAL source
// (rule #21: both-sides-or-neither).
#define GLDS16(gsrc, ldst) \
  __builtin_amdgcn_global_load_lds( \
      (const __attribute__((address_space(1))) unsigned int*)(gsrc), \
      (__attribute__((address_space(3))) unsigned int*)(ldst), 16, 0, 0)

// ---------------- Kernel A: h = silu(x@w1^T + b1) * (x@w3^T + b3) ------------
// FINAL (R17 binary, best-measured: 483.5/483.8/514.2): BM=BN=128, BK=64,
// 8 waves 4x2, 96 KB dbuf, 1 blk/CU, monolithic single-barrier K-step,
// GLOAD-pinned loads(t+2), rA/c staging with 6 x ds_write_b128 per thread.
__global__ __launch_bounds__(512) void moe_h_kernel(
    const float* __restrict__ x, const int* __restrict__ idxs,
    const float* __restrict__ w1w, const float* __restrict__ w1b,
    const float* __restrict__ w3w, const float* __restrict__ w3b,
    __bf16* __restrict__ hbuf)
{
  __shared__ __align__(16) ushort sA [2][128*64];
  __shared__ __align__(16) ushort sB1[2][128*64];
  __shared__ __align__(16) ushort sB3[2][128*64];   // 96 KB

  // XCD swizzle: 2048 blocks, 256/XCD
  const int blk = (blockIdx.x & 7) * (NEXP*16/8) + (blockIdx.x >> 3);
  const int e   = blk >> 4;
  const int tl  = blk & 15;
  const int tm  = tl >> 2, tn = tl & 3;

  const int tid  = threadIdx.x;
  const int lane = tid & 63;
  const int wid  = tid >> 6;
  const int wm   = wid >> 1;       // 0..3 -> 32-row slice
  const int wn   = wid & 1;        // 0..1 -> 64-col slice

  // staging: thread (row rA & rA+64, 16B-chunk c); 8 chunks per 64-elem row
  const int rA = tid >> 3;         // 0..63
  const int c  = tid & 7;          // 0..7
  const int swzc = ((c ^ (rA&7))<<3);          // (rA+64)&7 == rA&7
  const int so0 = rA*64 + swzc;
  const int so1 = (rA+64)*64 + swzc;

  const int tok0 = idxs[e*TPE + tm*128 + rA];
  const int tok1 = idxs[e*TPE + tm*128 + rA + 64];
  const float* ap0 = x + (size_t)tok0*IN_CH + (c<<3);
  const float* ap1 = x + (size_t)tok1*IN_CH + (c<<3);
  const float* q0p = w1w + ((size_t)e*INTER + tn*128 + rA)*IN_CH + (c<<3);
  const float* q1p = q0p + (size_t)64*IN_CH;
  const float* t0p = w3w + ((size_t)e*INTER + tn*128 + rA)*IN_CH + (c<<3);
  const float* t1p = t0p + (size_t)64*IN_CH;

  f32x4 acc1[2][4], acc3[2][4];
#pragma unroll
  for (int a = 0; a < 2; ++a)
#pragma unroll
    for (int b = 0; b < 4; ++b) {
      acc1[a][b] = (f32x4){0.f,0.f,0.f,0.f};
      acc3[a][b] = (f32x4){0.f,0.f,0.f,0.f};
    }

  // 12 f32x4 staging regs (48 VGPR), asm-pinned
  f32x4 a0l,a0h, a1l,a1h, q0l,q0h, q1l,q1h, t0l,t0h, t1l,t1h;

  auto loads = [&](int kof) {
    GLOAD(a0l, ap0 + kof); GLOAD(a0h, ap0 + kof + 4);
    GLOAD(a1l, ap1 + kof); GLOAD(a1h, ap1 + kof + 4);
    GLOAD(q0l, q0p + kof); GLOAD(q0h, q0p + kof + 4);
    GLOAD(q1l, q1p + kof); GLOAD(q1h, q1p + kof + 4);
    GLOAD(t0l, t0p + kof); GLOAD(t0h, t0p + kof + 4);
    GLOAD(t1l, t1p + kof); GLOAD(t1h, t1p + kof + 4);
  };
  auto cvt8 = [](const f32x4& lo, const f32x4& hi) {
    bf16x8 r;
    r[0]=(__bf16)lo[0]; r[1]=(__bf16)lo[1]; r[2]=(__bf16)lo[2]; r[3]=(__bf16)lo[3];
    r[4]=(__bf16)hi[0]; r[5]=(__bf16)hi[1]; r[6]=(__bf16)hi[2]; r[7]=(__bf16)hi[3];
    return r;
  };
  auto stores = [&](int buf) {
    VM_WAIT();
    *(bf16x8*)&sA [buf][so0] = cvt8(a0l, a0h);
    *(bf16x8*)&sA [buf][so1] = cvt8(a1l, a1h);
    *(bf16x8*)&sB1[buf][so0] = cvt8(q0l, q0h);
    *(bf16x8*)&sB1[buf][so1] = cvt8(q1l, q1h);
    *(bf16x8*)&sB3[buf][so0] = cvt8(t0l, t0h);
    *(bf16x8*)&sB3[buf][so1] = cvt8(t1l, t1h);
  };
  auto mfma_tile = [&](int buf) {
#pragma unroll
    for (int ks = 0; ks < 2; ++ks) {
      bf16x8 af[2], bq[4], bt[4];
      const int k8 = (ks<<2) + (lane>>4);
#pragma unroll
      for (int mi = 0; mi < 2; ++mi) {
        const int r = wm*32 + mi*16 + (lane&15);
        af[mi] = *(const bf16x8*)&sA[buf][r*64 + ((k8 ^ (r&7))<<3)];
      }
#pragma unroll
      for (int ni = 0; ni < 4; ++ni) {
        const int r   = wn*64 + ni*16 + (lane&15);
        const int off = r*64 + ((k8 ^ (r&7))<<3);
        bq[ni] = *(const bf16x8*)&sB1[buf][off];
        bt[ni] = *(const bf16x8*)&sB3[buf][off];
      }
#pragma unroll
      for (int mi = 0; mi < 2; ++mi)
#pragma unroll
        for (int ni = 0; ni < 4; ++ni) {
          acc1[mi][ni] = __builtin_amdgcn_mfma_f32_16x16x32_bf16(af[mi], bq[ni], acc1[mi][ni], 0, 0, 0);
          acc3[mi][ni] = __builtin_amdgcn_mfma_f32_16x16x32_bf16(af[mi], bt[ni], acc3[mi][ni], 0, 0, 0);
        }
    }
  };

  loads(0);
  stores(0);
  loads(64);
  asm volatile("s_waitcnt lgkmcnt(0)" ::: "memory");
  __builtin_amdgcn_s_barrier();

  int cur = 0;
  const int NT = IN_CH/64;
  for (int kt = 0; kt < NT; ++kt) {
    if (kt < NT - 1) stores(cur ^ 1);
    if (kt < NT - 2) loads((kt+2)*64);
    __builtin_amdgcn_s_setprio(1);
    mfma_tile(cur);
    __builtin_amdgcn_s_setprio(0);
    asm volatile("s_waitcnt lgkmcnt(0)" ::: "memory");
    __builtin_amdgcn_s_barrier();
    cur ^= 1;
  }

  // epilogue: bias + SwiGLU, store bf16 h tile
  const int rowbase = tm*128 + wm*32;
  const int colbase = tn*128 + wn*64;
#pragma unroll
  for (int ni = 0; ni < 4; ++ni) {
    const int fc = colbase + ni*16 + (lane&15);
    const float b1v = w1b[e*INTER + fc];
    const float b3v = w3b[e*INTER + fc];
#pragma unroll
    for (int mi = 0; mi < 2; ++mi) {
#pragma unroll
      for (int j = 0; j < 4; ++j) {
        const int rl = rowbase + mi*16 + ((lane>>4)<<2) + j;
        const float h1 = acc1[mi][ni][j] + b1v;
        const float h3 = acc3[mi][ni][j] + b3v;
        const float s  = h1 / (1.0f + __expf(-h1));
        hbuf[((size_t)e*TPE + rl)*INTER + fc] = (__bf16)(s * h3);
      }
    }
  }
}

// ---------------- Kernel B: out = h @ w2^T + b2, scattered via idxs ----------
// R17 VERBATIM: A (h, bf16) staged via global_load_lds width=16 into LINEAR
// LDS with inverse-swizzled global source; counted vmcnt(4) keeps B(t+2) in
// flight across the A-completion wait.
__global__ __launch_bounds__(512) void moe_out_kernel(
    const __bf16* __restrict__ hbuf, const float* __restrict__ w2w,
    const float* __restrict__ w2b, const int* __restrict__ idxs,
    float* __restrict__ out)
{
  __shared__ __align__(16) ushort sA[2][128*64];
  __shared__ __align__(16) ushort sB[2][128*64];

  const int blk = (blockIdx.x & 7) * (NEXP*32/8) + (blockIdx.x >> 3);
  const int e   = blk >> 5;
  const int tl  = blk & 31;
  const int tm  = tl >> 3, tn = tl & 7;

  const int tid  = threadIdx.x;
  const int lane = tid & 63;
  const int wid  = tid >> 6;
  const int wm   = wid >> 1;       // 0..3
  const int wn   = wid & 1;        // 0..1

  // A via gload_lds: wave wid stages rows wid*16..wid*16+15 (2 insts of
  // 64 lanes x 16B). Lane covers LDS slot (row = wid*16+i*8+(lane>>3),
  // stored chunk = lane&7); global src chunk = (lane&7) ^ (row&7).
  const int arow0 = wid*16 + (lane>>3);          // i=0 row (block-local)
  const int asc0  = (lane&7) ^ (arow0&7);
  const int asc1  = (lane&7) ^ ((arow0+8)&7);
  const __bf16* ag0 = hbuf + ((size_t)e*TPE + tm*128 + arow0    )*INTER + (asc0<<3);
  const __bf16* ag1 = hbuf + ((size_t)e*TPE + tm*128 + arow0 + 8)*INTER + (asc1<<3);
  const int aslot0 = (wid*128)      * 8;         // ushort index of wave region
  const int aslot1 = (wid*128 + 64) * 8;

  // B (w2 fp32 -> bf16): reg-staged
  const int r0   = tid >> 4;          // 0..31
  const int c4   = tid & 15;
  const int swzB = ((((c4>>1) ^ (r0&7))<<3) | ((c4&1)<<2));
  const float* bp = w2w + ((size_t)e*IN_CH + tn*128 + r0)*INTER + (c4<<2);

  f32x4 acc[2][4];
#pragma unroll
  for (int a = 0; a < 2; ++a)
#pragma unroll
    for (int b = 0; b < 4; ++b) acc[a][b] = (f32x4){0.f,0.f,0.f,0.f};

  float4 wv[4];

  auto gldsA = [&](int buf, int kof) {
    GLDS16(ag0 + kof, &sA[buf][aslot0]);
    GLDS16(ag1 + kof, &sA[buf][aslot1]);
  };
  auto loadsB = [&](int kof) {
#pragma unroll
    for (int i = 0; i < 4; ++i)
      wv[i] = *(const float4*)(bp + (size_t)(32*i)*INTER + kof);
  };
  auto storesB = [&](int buf) {
#pragma unroll
    for (int i = 0; i < 4; ++i) {
      bf16x4v b;
      b[0]=(__bf16)wv[i].x; b[1]=(__bf16)wv[i].y; b[2]=(__bf16)wv[i].z; b[3]=(__bf16)wv[i].w;
      *(bf16x4v*)&sB[buf][(r0 + 32*i)*64 + swzB] = b;
    }
  };
  auto rdA = [&](int buf, int ks, bf16x8 af[2]) {
    const int k8 = (ks<<2) + (lane>>4);
#pragma unroll
    for (int mi = 0; mi < 2; ++mi) {
      const int r = wm*32 + mi*16 + (lane&15);
      af[mi] = *(const bf16x8*)&sA[buf][r*64 + ((k8 ^ (r&7))<<3)];
    }
  };
  auto rdB = [&](int buf, int ks, bf16x8 bfr[4]) {
    const int k8 = (ks<<2) + (lane>>4);
#pragma unroll
    for (int ni = 0; ni < 4; ++ni) {
      const int r = wn*64 + ni*16 + (lane&15);
      bfr[ni] = *(const bf16x8*)&sB[buf][r*64 + ((k8 ^ (r&7))<<3)];
    }
  };

  // prologue: A(t0) via gload_lds + B(t0) regs; drain; stage B; B(t1) ahead
  gldsA(0, 0);
  loadsB(0);
  VM_WAIT();
  storesB(0);
  loadsB(64);
  asm volatile("s_waitcnt lgkmcnt(0)" ::: "memory");
  __builtin_amdgcn_s_barrier();

  int cur = 0;
  const int NT = INTER/64;
  for (int kt = 0; kt < NT; ++kt) {
    bf16x8 af[2], bfr[4];

    // P0: reads ks0 | drain B(t+1) regs -> sB(t+1) | issue A-glds(t+1) |
    //     issue B(t+2)
    rdA(cur, 0, af);
    rdB(cur, 0, bfr);
    if (kt < NT - 1) {
      VM_WAIT();                       // B(t+1) landed (2 phases in flight)
      storesB(cur ^ 1);
      gldsA(cur ^ 1, (kt+1)*64);
      __builtin_amdgcn_sched_barrier(0);   // pin glds before B loads (vmcnt order)
    }
    if (kt < NT - 2) loadsB((kt+2)*64);
    PHASE_SYNC();
#pragma unroll
    for (int mi = 0; mi < 2; ++mi)
#pragma unroll
      for (int ni = 0; ni < 4; ++ni)
        acc[mi][ni] = __builtin_amdgcn_mfma_f32_16x16x32_bf16(af[mi], bfr[ni], acc[mi][ni], 0, 0, 0);
    PHASE_END();

    // P1: reads ks1; before final barrier guarantee A-glds(t+1) complete
    // (vmcnt(4) leaves the 4 B(t+2) loads in flight)
    rdA(cur, 1, af);
    rdB(cur, 1, bfr);
    PHASE_SYNC();
#pragma unroll
    for (int mi = 0; mi < 2; ++mi)
#pragma unroll
      for (int ni = 0; ni < 4; ++ni)
        acc[mi][ni] = __builtin_amdgcn_mfma_f32_16x16x32_bf16(af[mi], bfr[ni], acc[mi][ni], 0, 0, 0);
    __builtin_amdgcn_s_setprio(0);
    if (kt < NT - 2)      asm volatile("s_waitcnt vmcnt(4)" ::: "memory");
    else if (kt < NT - 1) asm volatile("s_waitcnt vmcnt(0)" ::: "memory");
    __builtin_amdgcn_s_barrier();

    cur ^= 1;
  }

  const int rowbase = tm*128 + wm*32;
  const int colbase = tn*128 + wn*64;
  float b2v[4];
#pragma unroll
  for (int ni = 0; ni < 4; ++ni)
    b2v[ni] = w2b[e*IN_CH + colbase + ni*16 + (lane&15)];
#pragma unroll
  for (int mi = 0; mi < 2; ++mi) {
#pragma unroll
    for (int j = 0; j < 4; ++j) {
      const int rl  = rowbase + mi*16 + ((lane>>4)<<2) + j;
      const int tok = idxs[e*TPE + rl];
      float* orow = out + (size_t)tok*IN_CH;
#pragma unroll
      for (int ni = 0; ni < 4; ++ni)
        orow[colbase + ni*16 + (lane&15)] = acc[mi][ni][j] + b2v[ni];
    }
  }
}

extern "C" void kernel_launch(void* const* d_in, const int* in_sizes, int n_in,
                              void* d_out, int out_size, void* d_ws, size_t ws_size,
                              hipStream_t stream) {
  const float* x    = (const float*)d_in[0];
  const int*   idxs = (const int*)d_in[1];
  const float* w1w  = (const float*)d_in[2];
  const float* w1b  = (const float*)d_in[3];
  const float* w2w  = (const float*)d_in[4];
  const float* w2b  = (const float*)d_in[5];
  const float* w3w  = (const float*)d_in[6];
  const float* w3b  = (const float*)d_in[7];
  float*  out  = (float*)d_out;
  __bf16* hbuf = (__bf16*)d_ws;   // 128*512*512 bf16 = 64 MB intermediate

  moe_h_kernel<<<dim3(NEXP*16), dim3(512), 0, stream>>>(x, idxs, w1w, w1b, w3w, w3b, hbuf);
  moe_out_kernel<<<dim3(NEXP*32), dim3(512), 0, stream>>>(hbuf, w2w, w2b, idxs, out);
}

// Round 25
// 482.364 us; speedup vs baseline: 1.0960x; 1.0004x over previous
//
#include <hip/hip_runtime.h>

#define IN_CH 1024
#define INTER 512
#define NEXP  128
#define TPE   512

typedef __bf16 bf16x8  __attribute__((ext_vector_type(8)));
typedef __bf16 bf16x4v __attribute__((ext_vector_type(4)));
typedef float  f32x4   __attribute__((ext_vector_type(4)));

// ISA-pinned staging load ("=&v" early-clobber: R8 abort lesson; never let
// these spill -> 1 blk/CU only, R9 NaN lesson).
#define GLOAD(dst, p) \
  asm volatile("global_load_dwordx4 %0, %1, off" : "=&v"(dst) : "v"(p))

// vmcnt wait + scheduler fence (rule #18).
#define VM_WAIT() do { \
  asm volatile("s_waitcnt vmcnt(0)" ::: "memory"); \
  __builtin_amdgcn_sched_barrier(0); } while (0)

#define PHASE_SYNC() do { \
  __builtin_amdgcn_s_barrier(); \
  asm volatile("s_waitcnt lgkmcnt(0)" ::: "memory"); \
  __builtin_amdgcn_sched_barrier(0); \
  __builtin_amdgcn_s_setprio(1); } while (0)
#define PHASE_END() do { \
  __builtin_amdgcn_s_setprio(0); \
  __builtin_amdgcn_s_barrier(); } while (0)

// Async global->LDS, 16B per lane: LDS dest = wave-uniform base + lane*16
// (linear); swizzle achieved by inverse-permuting the per-lane GLOBAL source
// (rule #21: both-sides-or-neither).
#define GLDS16(gsrc, ldst) \
  __builtin_amdgcn_global_load_lds( \
      (const __attribute__((address_space(1))) unsigned int*)(gsrc), \
      (__attribute__((address_space(3))) unsigned int*)(ldst), 16, 0, 0)

// ---------------- Kernel A: h = silu(x@w1^T + b1) * (x@w3^T + b3) ------------
// FINAL (best-measured binary: 482.5/483.5/483.8/514.2): BM=BN=128, BK=64,
// 8 waves 4x2, 96 KB dbuf, 1 blk/CU, monolithic single-barrier K-step,
// GLOAD-pinned loads(t+2), rA/c staging with 6 x ds_write_b128 per thread.
__global__ __launch_bounds__(512) void moe_h_kernel(
    const float* __restrict__ x, const int* __restrict__ idxs,
    const float* __restrict__ w1w, const float* __restrict__ w1b,
    const float* __restrict__ w3w, const float* __restrict__ w3b,
    __bf16* __restrict__ hbuf)
{
  __shared__ __align__(16) ushort sA [2][128*64];
  __shared__ __align__(16) ushort sB1[2][128*64];
  __shared__ __align__(16) ushort sB3[2][128*64];   // 96 KB

  // XCD swizzle: 2048 blocks, 256/XCD
  const int blk = (blockIdx.x & 7) * (NEXP*16/8) + (blockIdx.x >> 3);
  const int e   = blk >> 4;
  const int tl  = blk & 15;
  const int tm  = tl >> 2, tn = tl & 3;

  const int tid  = threadIdx.x;
  const int lane = tid & 63;
  const int wid  = tid >> 6;
  const int wm   = wid >> 1;       // 0..3 -> 32-row slice
  const int wn   = wid & 1;        // 0..1 -> 64-col slice

  // staging: thread (row rA & rA+64, 16B-chunk c); 8 chunks per 64-elem row
  const int rA = tid >> 3;         // 0..63
  const int c  = tid & 7;          // 0..7
  const int swzc = ((c ^ (rA&7))<<3);          // (rA+64)&7 == rA&7
  const int so0 = rA*64 + swzc;
  const int so1 = (rA+64)*64 + swzc;

  const int tok0 = idxs[e*TPE + tm*128 + rA];
  const int tok1 = idxs[e*TPE + tm*128 + rA + 64];
  const float* ap0 = x + (size_t)tok0*IN_CH + (c<<3);
  const float* ap1 = x + (size_t)tok1*IN_CH + (c<<3);
  const float* q0p = w1w + ((size_t)e*INTER + tn*128 + rA)*IN_CH + (c<<3);
  const float* q1p = q0p + (size_t)64*IN_CH;
  const float* t0p = w3w + ((size_t)e*INTER + tn*128 + rA)*IN_CH + (c<<3);
  const float* t1p = t0p + (size_t)64*IN_CH;

  f32x4 acc1[2][4], acc3[2][4];
#pragma unroll
  for (int a = 0; a < 2; ++a)
#pragma unroll
    for (int b = 0; b < 4; ++b) {
      acc1[a][b] = (f32x4){0.f,0.f,0.f,0.f};
      acc3[a][b] = (f32x4){0.f,0.f,0.f,0.f};
    }

  // 12 f32x4 staging regs (48 VGPR), asm-pinned
  f32x4 a0l,a0h, a1l,a1h, q0l,q0h, q1l,q1h, t0l,t0h, t1l,t1h;

  auto loads = [&](int kof) {
    GLOAD(a0l, ap0 + kof); GLOAD(a0h, ap0 + kof + 4);
    GLOAD(a1l, ap1 + kof); GLOAD(a1h, ap1 + kof + 4);
    GLOAD(q0l, q0p + kof); GLOAD(q0h, q0p + kof + 4);
    GLOAD(q1l, q1p + kof); GLOAD(q1h, q1p + kof + 4);
    GLOAD(t0l, t0p + kof); GLOAD(t0h, t0p + kof + 4);
    GLOAD(t1l, t1p + kof); GLOAD(t1h, t1p + kof + 4);
  };
  auto cvt8 = [](const f32x4& lo, const f32x4& hi) {
    bf16x8 r;
    r[0]=(__bf16)lo[0]; r[1]=(__bf16)lo[1]; r[2]=(__bf16)lo[2]; r[3]=(__bf16)lo[3];
    r[4]=(__bf16)hi[0]; r[5]=(__bf16)hi[1]; r[6]=(__bf16)hi[2]; r[7]=(__bf16)hi[3];
    return r;
  };
  auto stores = [&](int buf) {
    VM_WAIT();
    *(bf16x8*)&sA [buf][so0] = cvt8(a0l, a0h);
    *(bf16x8*)&sA [buf][so1] = cvt8(a1l, a1h);
    *(bf16x8*)&sB1[buf][so0] = cvt8(q0l, q0h);
    *(bf16x8*)&sB1[buf][so1] = cvt8(q1l, q1h);
    *(bf16x8*)&sB3[buf][so0] = cvt8(t0l, t0h);
    *(bf16x8*)&sB3[buf][so1] = cvt8(t1l, t1h);
  };
  auto mfma_tile = [&](int buf) {
#pragma unroll
    for (int ks = 0; ks < 2; ++ks) {
      bf16x8 af[2], bq[4], bt[4];
      const int k8 = (ks<<2) + (lane>>4);
#pragma unroll
      for (int mi = 0; mi < 2; ++mi) {
        const int r = wm*32 + mi*16 + (lane&15);
        af[mi] = *(const bf16x8*)&sA[buf][r*64 + ((k8 ^ (r&7))<<3)];
      }
#pragma unroll
      for (int ni = 0; ni < 4; ++ni) {
        const int r   = wn*64 + ni*16 + (lane&15);
        const int off = r*64 + ((k8 ^ (r&7))<<3);
        bq[ni] = *(const bf16x8*)&sB1[buf][off];
        bt[ni] = *(const bf16x8*)&sB3[buf][off];
      }
#pragma unroll
      for (int mi = 0; mi < 2; ++mi)
#pragma unroll
        for (int ni = 0; ni < 4; ++ni) {
          acc1[mi][ni] = __builtin_amdgcn_mfma_f32_16x16x32_bf16(af[mi], bq[ni], acc1[mi][ni], 0, 0, 0);
          acc3[mi][ni] = __builtin_amdgcn_mfma_f32_16x16x32_bf16(af[mi], bt[ni], acc3[mi][ni], 0, 0, 0);
        }
    }
  };

  loads(0);
  stores(0);
  loads(64);
  asm volatile("s_waitcnt lgkmcnt(0)" ::: "memory");
  __builtin_amdgcn_s_barrier();

  int cur = 0;
  const int NT = IN_CH/64;
  for (int kt = 0; kt < NT; ++kt) {
    if (kt < NT - 1) stores(cur ^ 1);
    if (kt < NT - 2) loads((kt+2)*64);
    __builtin_amdgcn_s_setprio(1);
    mfma_tile(cur);
    __builtin_amdgcn_s_setprio(0);
    asm volatile("s_waitcnt lgkmcnt(0)" ::: "memory");
    __builtin_amdgcn_s_barrier();
    cur ^= 1;
  }

  // epilogue: bias + SwiGLU, store bf16 h tile
  const int rowbase = tm*128 + wm*32;
  const int colbase = tn*128 + wn*64;
#pragma unroll
  for (int ni = 0; ni < 4; ++ni) {
    const int fc = colbase + ni*16 + (lane&15);
    const float b1v = w1b[e*INTER + fc];
    const float b3v = w3b[e*INTER + fc];
#pragma unroll
    for (int mi = 0; mi < 2; ++mi) {
#pragma unroll
      for (int j = 0; j < 4; ++j) {
        const int rl = rowbase + mi*16 + ((lane>>4)<<2) + j;
        const float h1 = acc1[mi][ni][j] + b1v;
        const float h3 = acc3[mi][ni][j] + b3v;
        const float s  = h1 / (1.0f + __expf(-h1));
        hbuf[((size_t)e*TPE + rl)*INTER + fc] = (__bf16)(s * h3);
      }
    }
  }
}

// ---------------- Kernel B: out = h @ w2^T + b2, scattered via idxs ----------
// A (h, bf16) staged via global_load_lds width=16 into LINEAR LDS with
// inverse-swizzled global source; counted vmcnt(4) keeps B(t+2) in flight
// across the A-completion wait.
__global__ __launch_bounds__(512) void moe_out_kernel(
    const __bf16* __restrict__ hbuf, const float* __restrict__ w2w,
    const float* __restrict__ w2b, const int* __restrict__ idxs,
    float* __restrict__ out)
{
  __shared__ __align__(16) ushort sA[2][128*64];
  __shared__ __align__(16) ushort sB[2][128*64];

  const int blk = (blockIdx.x & 7) * (NEXP*32/8) + (blockIdx.x >> 3);
  const int e   = blk >> 5;
  const int tl  = blk & 31;
  const int tm  = tl >> 3, tn = tl & 7;

  const int tid  = threadIdx.x;
  const int lane = tid & 63;
  const int wid  = tid >> 6;
  const int wm   = wid >> 1;       // 0..3
  const int wn   = wid & 1;        // 0..1

  // A via gload_lds: wave wid stages rows wid*16..wid*16+15 (2 insts of
  // 64 lanes x 16B). Lane covers LDS slot (row = wid*16+i*8+(lane>>3),
  // stored chunk = lane&7); global src chunk = (lane&7) ^ (row&7).
  const int arow0 = wid*16 + (lane>>3);          // i=0 row (block-local)
  const int asc0  = (lane&7) ^ (arow0&7);
  const int asc1  = (lane&7) ^ ((arow0+8)&7);
  const __bf16* ag0 = hbuf + ((size_t)e*TPE + tm*128 + arow0    )*INTER + (asc0<<3);
  const __bf16* ag1 = hbuf + ((size_t)e*TPE + tm*128 + arow0 + 8)*INTER + (asc1<<3);
  const int aslot0 = (wid*128)      * 8;         // ushort index of wave region
  const int aslot1 = (wid*128 + 64) * 8;

  // B (w2 fp32 -> bf16): reg-staged
  const int r0   = tid >> 4;          // 0..31
  const int c4   = tid & 15;
  const int swzB = ((((c4>>1) ^ (r0&7))<<3) | ((c4&1)<<2));
  const float* bp = w2w + ((size_t)e*IN_CH + tn*128 + r0)*INTER + (c4<<2);

  f32x4 acc[2][4];
#pragma unroll
  for (int a = 0; a < 2; ++a)
#pragma unroll
    for (int b = 0; b < 4; ++b) acc[a][b] = (f32x4){0.f,0.f,0.f,0.f};

  float4 wv[4];

  auto gldsA = [&](int buf, int kof) {
    GLDS16(ag0 + kof, &sA[buf][aslot0]);
    GLDS16(ag1 + kof, &sA[buf][aslot1]);
  };
  auto loadsB = [&](int kof) {
#pragma unroll
    for (int i = 0; i < 4; ++i)
      wv[i] = *(const float4*)(bp + (size_t)(32*i)*INTER + kof);
  };
  auto storesB = [&](int buf) {
#pragma unroll
    for (int i = 0; i < 4; ++i) {
      bf16x4v b;
      b[0]=(__bf16)wv[i].x; b[1]=(__bf16)wv[i].y; b[2]=(__bf16)wv[i].z; b[3]=(__bf16)wv[i].w;
      *(bf16x4v*)&sB[buf][(r0 + 32*i)*64 + swzB] = b;
    }
  };
  auto rdA = [&](int buf, int ks, bf16x8 af[2]) {
    const int k8 = (ks<<2) + (lane>>4);
#pragma unroll
    for (int mi = 0; mi < 2; ++mi) {
      const int r = wm*32 + mi*16 + (lane&15);
      af[mi] = *(const bf16x8*)&sA[buf][r*64 + ((k8 ^ (r&7))<<3)];
    }
  };
  auto rdB = [&](int buf, int ks, bf16x8 bfr[4]) {
    const int k8 = (ks<<2) + (lane>>4);
#pragma unroll
    for (int ni = 0; ni < 4; ++ni) {
      const int r = wn*64 + ni*16 + (lane&15);
      bfr[ni] = *(const bf16x8*)&sB[buf][r*64 + ((k8 ^ (r&7))<<3)];
    }
  };

  // prologue: A(t0) via gload_lds + B(t0) regs; drain; stage B; B(t1) ahead
  gldsA(0, 0);
  loadsB(0);
  VM_WAIT();
  storesB(0);
  loadsB(64);
  asm volatile("s_waitcnt lgkmcnt(0)" ::: "memory");
  __builtin_amdgcn_s_barrier();

  int cur = 0;
  const int NT = INTER/64;
  for (int kt = 0; kt < NT; ++kt) {
    bf16x8 af[2], bfr[4];

    // P0: reads ks0 | drain B(t+1) regs -> sB(t+1) | issue A-glds(t+1) |
    //     issue B(t+2)
    rdA(cur, 0, af);
    rdB(cur, 0, bfr);
    if (kt < NT - 1) {
      VM_WAIT();                       // B(t+1) landed (2 phases in flight)
      storesB(cur ^ 1);
      gldsA(cur ^ 1, (kt+1)*64);
      __builtin_amdgcn_sched_barrier(0);   // pin glds before B loads (vmcnt order)
    }
    if (kt < NT - 2) loadsB((kt+2)*64);
    PHASE_SYNC();
#pragma unroll
    for (int mi = 0; mi < 2; ++mi)
#pragma unroll
      for (int ni = 0; ni < 4; ++ni)
        acc[mi][ni] = __builtin_amdgcn_mfma_f32_16x16x32_bf16(af[mi], bfr[ni], acc[mi][ni], 0, 0, 0);
    PHASE_END();

    // P1: reads ks1; before final barrier guarantee A-glds(t+1) complete
    // (vmcnt(4) leaves the 4 B(t+2) loads in flight)
    rdA(cur, 1, af);
    rdB(cur, 1, bfr);
    PHASE_SYNC();
#pragma unroll
    for (int mi = 0; mi < 2; ++mi)
#pragma unroll
      for (int ni = 0; ni < 4; ++ni)
        acc[mi][ni] = __builtin_amdgcn_mfma_f32_16x16x32_bf16(af[mi], bfr[ni], acc[mi][ni], 0, 0, 0);
    __builtin_amdgcn_s_setprio(0);
    if (kt < NT - 2)      asm volatile("s_waitcnt vmcnt(4)" ::: "memory");
    else if (kt < NT - 1) asm volatile("s_waitcnt vmcnt(0)" ::: "memory");
    __builtin_amdgcn_s_barrier();

    cur ^= 1;
  }

  const int rowbase = tm*128 + wm*32;
  const int colbase = tn*128 + wn*64;
  float b2v[4];
#pragma unroll
  for (int ni = 0; ni < 4; ++ni)
    b2v[ni] = w2b[e*IN_CH + colbase + ni*16 + (lane&15)];
#pragma unroll
  for (int mi = 0; mi < 2; ++mi) {
#pragma unroll
    for (int j = 0; j < 4; ++j) {
      const int rl  = rowbase + mi*16 + ((lane>>4)<<2) + j;
      const int tok = idxs[e*TPE + rl];
      float* orow = out + (size_t)tok*IN_CH;
#pragma unroll
      for (int ni = 0; ni < 4; ++ni)
        orow[colbase + ni*16 + (lane&15)] = acc[mi][ni][j] + b2v[ni];
    }
  }
}

extern "C" void kernel_launch(void* const* d_in, const int* in_sizes, int n_in,
                              void* d_out, int out_size, void* d_ws, size_t ws_size,
                              hipStream_t stream) {
  const float* x    = (const float*)d_in[0];
  const int*   idxs = (const int*)d_in[1];
  const float* w1w  = (const float*)d_in[2];
  const float* w1b  = (const float*)d_in[3];
  const float* w2w  = (const float*)d_in[4];
  const float* w2b  = (const float*)d_in[5];
  const float* w3w  = (const float*)d_in[6];
  const float* w3b  = (const float*)d_in[7];
  float*  out  = (float*)d_out;
  __bf16* hbuf = (__bf16*)d_ws;   // 128*512*512 bf16 = 64 MB intermediate

  moe_h_kernel<<<dim3(NEXP*16), dim3(512), 0, stream>>>(x, idxs, w1w, w1b, w3w, w3b, hbuf);
  moe_out_kernel<<<dim3(NEXP*32), dim3(512), 0, stream>>>(hbuf, w2w, w2b, idxs, out);
}